// Round 3
// baseline (809.993 us; speedup 1.0000x reference)
//
#include <hip/hip_runtime.h>
#include <math.h>

#define Bsz 1024
#define PADL 127
#define HID 512
#define NBb 128
#define NYd 8
#define INDIM 640
#define MTRIP 10
#define MROW 8
#define NBNY 1024
#define FOURH 2048

__device__ __forceinline__ float sigf(float x){ return 1.0f/(1.0f+expf(-x)); }

// =====================================================================
// GEMM: C[M][ldc] = A1@B1^T (+ A2@B2^T) + bias1 (+ bias2)
// A row-major [M][K], B row-major [N][K] (torch weight layout), lda==K.
// Tile: BM x 64, BK=16, 256 threads, microtile TM x 4.
// Double-buffered LDS + register prefetch (issue-early / write-late).
// =====================================================================
template<int TM>
__global__ __launch_bounds__(256) void gemm_bias(
    const float* __restrict__ A1, const float* __restrict__ B1, int K1,
    const float* __restrict__ A2, const float* __restrict__ B2, int K2,
    const float* __restrict__ bias1, const float* __restrict__ bias2,
    float* __restrict__ C, int ldc)
{
    constexpr int BM = TM*16;           // 128 (TM=8) or 64 (TM=4)
    __shared__ float As[2][16][BM+4];
    __shared__ float Bs[2][16][68];
    const int tid = threadIdx.x;
    const int m0 = blockIdx.y*BM, n0 = blockIdx.x*64;

    // A staging map: BM*16 floats / 256 threads = TM floats per thread
    const int ar = (TM==8) ? (tid>>1) : (tid>>2);
    const int ac = (TM==8) ? ((tid&1)*8) : ((tid&3)*4);
    // B staging map: 64*16/256 = 4 floats per thread
    const int br = tid>>2, bc = (tid&3)*4;

    const int tm = (tid>>4)*TM, tn = (tid&15)*4;

    float acc[TM][4];
    #pragma unroll
    for (int i=0;i<TM;i++){
        #pragma unroll
        for (int j=0;j<4;j++) acc[i][j]=0.f;
    }

    const int P1 = K1/16;
    const int nsteps = P1 + K2/16;

    float4 pa0, pa1, pb0;
    auto prefetch = [&](int s){
        const float* A; const float* B; int K; int k0;
        if (s < P1){ A=A1; B=B1; K=K1; k0 = s*16; }
        else       { A=A2; B=B2; K=K2; k0 = (s-P1)*16; }
        const float* ap = A + (size_t)(m0+ar)*K + k0 + ac;
        pa0 = *(const float4*)ap;
        if (TM==8) pa1 = *(const float4*)(ap+4);
        pb0 = *(const float4*)(B + (size_t)(n0+br)*K + k0 + bc);
    };
    auto stage = [&](int buf){
        As[buf][ac+0][ar]=pa0.x; As[buf][ac+1][ar]=pa0.y;
        As[buf][ac+2][ar]=pa0.z; As[buf][ac+3][ar]=pa0.w;
        if (TM==8){
            As[buf][ac+4][ar]=pa1.x; As[buf][ac+5][ar]=pa1.y;
            As[buf][ac+6][ar]=pa1.z; As[buf][ac+7][ar]=pa1.w;
        }
        Bs[buf][bc+0][br]=pb0.x; Bs[buf][bc+1][br]=pb0.y;
        Bs[buf][bc+2][br]=pb0.z; Bs[buf][bc+3][br]=pb0.w;
    };

    prefetch(0);
    stage(0);
    __syncthreads();
    int buf = 0;
    for (int s=0; s<nsteps; ++s){
        if (s+1 < nsteps) prefetch(s+1);
        #pragma unroll
        for (int kk=0; kk<16; ++kk){
            float a[TM], b[4];
            #pragma unroll
            for (int i=0;i<TM;i++) a[i] = As[buf][kk][tm+i];
            #pragma unroll
            for (int j=0;j<4;j++)  b[j] = Bs[buf][kk][tn+j];
            #pragma unroll
            for (int i=0;i<TM;i++)
                #pragma unroll
                for (int j=0;j<4;j++) acc[i][j] += a[i]*b[j];
        }
        if (s+1 < nsteps){
            stage(buf^1);
            __syncthreads();
            buf ^= 1;
        }
    }

    #pragma unroll
    for (int i=0;i<TM;i++){
        int row = m0+tm+i;
        #pragma unroll
        for (int j=0;j<4;j++){
            int col = n0+tn+j;
            float bsum = bias1[col] + (bias2 ? bias2[col] : 0.f);
            C[(size_t)row*ldc + col] = acc[i][j] + bsum;
        }
    }
}

// ---- LSTM elementwise (float4): h = sig(o)*tanh(sig(f)*c0 + sig(i)*tanh(g)) ----
__global__ __launch_bounds__(256) void lstm_kernel(const float* __restrict__ gates,
    const float* __restrict__ c0, float* __restrict__ h)
{
    int idx = blockIdx.x*256 + threadIdx.x;       // < 1024*128
    int b = idx >> 7, j4 = (idx & 127)*4;
    const float* g = gates + (size_t)b*FOURH;
    float4 iv = *(const float4*)(g + j4);
    float4 fv = *(const float4*)(g + 512 + j4);
    float4 gv = *(const float4*)(g + 1024 + j4);
    float4 ov = *(const float4*)(g + 1536 + j4);
    float4 cv = *(const float4*)(c0 + (size_t)b*HID + j4);
    float4 hv;
    hv.x = sigf(ov.x)*tanhf(sigf(fv.x)*cv.x + sigf(iv.x)*tanhf(gv.x));
    hv.y = sigf(ov.y)*tanhf(sigf(fv.y)*cv.y + sigf(iv.y)*tanhf(gv.y));
    hv.z = sigf(ov.z)*tanhf(sigf(fv.z)*cv.z + sigf(iv.z)*tanhf(gv.z));
    hv.w = sigf(ov.w)*tanhf(sigf(fv.w)*cv.w + sigf(iv.w)*tanhf(gv.w));
    *(float4*)(h + (size_t)b*HID + j4) = hv;
}

// ---- any(encoder_mask row) with 4-int-chunk early exit ----
__device__ __forceinline__ int row_any(const int* __restrict__ p){
    #pragma unroll 1
    for (int j=0; j<124; j+=4){
        if (p[j] | p[j+1] | p[j+2] | p[j+3]) return 1;
    }
    return (p[124] | p[125] | p[126]) ? 1 : 0;
}

// ---- fused: yard feasibility + masked softmax + argmax + decode ----
__global__ __launch_bounds__(256) void softmax_fused(
    const float* __restrict__ logits, const int* __restrict__ em,
    const int* __restrict__ bmask, const int* __restrict__ bcount,
    const float* __restrict__ bsize, const float* __restrict__ bwid_in,
    const float* __restrict__ blen_in,
    float* __restrict__ probs,
    int* __restrict__ pslot, int* __restrict__ pblock,
    float* __restrict__ pblen, float* __restrict__ pbwid)
{
    int b = blockIdx.x, t = threadIdx.x;
    __shared__ float red[256];
    __shared__ int  redi[256];
    const float* lrow = logits + (size_t)b*NBNY;

    float ml[4]; float mymax = -INFINITY;
    #pragma unroll
    for (int r=0;r<4;++r){
        int c = t + r*256;
        int nb = c >> 3;
        int v = 0;
        if (bmask[b*NBb + nb] == 0)
            v = row_any(em + (size_t)(b*NBNY + c)*PADL);
        float m = v ? lrow[c] : -1e9f;
        ml[r] = m; mymax = fmaxf(mymax, m);
    }
    red[t]=mymax; __syncthreads();
    for (int s=128;s>0;s>>=1){ if(t<s) red[t]=fmaxf(red[t],red[t+s]); __syncthreads(); }
    float rowmax = red[0]; __syncthreads();

    float p[4]; float mysum=0.f;
    #pragma unroll
    for (int r=0;r<4;++r){ p[r]=expf(ml[r]-rowmax); mysum+=p[r]; }
    red[t]=mysum; __syncthreads();
    for (int s=128;s>0;s>>=1){ if(t<s) red[t]+=red[t+s]; __syncthreads(); }
    float inv = 1.0f/red[0]; __syncthreads();

    float bv=-INFINITY; int bi=0;
    #pragma unroll
    for (int r=0;r<4;++r){
        int c = t + r*256;
        float pr = p[r]*inv;
        probs[(size_t)b*NBNY + c] = pr;
        if (pr > bv){ bv=pr; bi=c; }     // in-thread cols ascend -> strict > = first max
    }
    red[t]=bv; redi[t]=bi; __syncthreads();
    for (int s=128;s>0;s>>=1){
        if (t<s){
            float ov=red[t+s]; int oi=redi[t+s];
            if (ov>red[t] || (ov==red[t] && oi<redi[t])){ red[t]=ov; redi[t]=oi; }
        }
        __syncthreads();
    }

    if (t==0){
        int a = redi[0];
        int blk = a / NYd, yard = a % NYd;
        int cur = bcount[b*NYd + yard];
        int base = ((b*NYd + yard)*MTRIP + cur)*MROW;
        float bestv = -INFINITY; int bests = 0;
        #pragma unroll
        for (int s=0;s<MROW;++s){
            float w = bwid_in[base+s];
            float l = blen_in[base+s];
            float cand = (w <= 10.0f) ? l : -1.0f;
            if (cand > bestv){ bestv=cand; bests=s; }   // first max
        }
        pslot[b]  = base + bests;
        pblock[b] = blk;
        pblen[b]  = bsize[(b*NBb + blk)*5 + 0];
        pbwid[b]  = bsize[(b*NBb + blk)*5 + 1];
    }
}

// ---- copy inputs -> outputs with single-element patches ----
__global__ __launch_bounds__(256) void finalize_kernel(const int* __restrict__ bslot,
    const float* __restrict__ blen_in, const float* __restrict__ bwid_in,
    const int* __restrict__ pslot, const int* __restrict__ pblock,
    const float* __restrict__ pblen, const float* __restrict__ pbwid,
    float* __restrict__ out_slot, float* __restrict__ out_len, float* __restrict__ out_wid)
{
    int i = blockIdx.x*256 + threadIdx.x;
    if (i < Bsz*NYd*MTRIP*MROW*2){               // 1,310,720
        int b = i / (NYd*MTRIP*MROW*2);          // /1280
        float v = (float)bslot[i];
        if (i == pslot[b]*2 + 1) v = (float)pblock[b];
        out_slot[i] = v;
    }
    if (i < Bsz*NYd*MTRIP*MROW){                 // 655,360
        int b = i / (NYd*MTRIP*MROW);            // /640
        float l = blen_in[i], w = bwid_in[i];
        if (i == pslot[b]){ l = fmaxf(l, pblen[b]); w = w + pbwid[b]; }
        out_len[i] = l;
        out_wid[i] = w;
    }
}

extern "C" void kernel_launch(void* const* d_in, const int* in_sizes, int n_in,
                              void* d_out, int out_size, void* d_ws, size_t ws_size,
                              hipStream_t stream)
{
    const float* x    = (const float*)d_in[0];
    const float* h0   = (const float*)d_in[1];
    const float* c0   = (const float*)d_in[2];
    const float* Wih  = (const float*)d_in[3];
    const float* Whh  = (const float*)d_in[4];
    const float* bih  = (const float*)d_in[5];
    const float* bhh  = (const float*)d_in[6];
    const float* Wfc  = (const float*)d_in[7];
    const float* bfc  = (const float*)d_in[8];
    const float* bsize= (const float*)d_in[9];
    const float* blen = (const float*)d_in[10];
    const float* bwid = (const float*)d_in[11];
    const int*   em   = (const int*)d_in[12];
    const int*   bmask= (const int*)d_in[13];
    const int*   bcount=(const int*)d_in[14];
    const int*   bslot= (const int*)d_in[15];

    float* out      = (float*)d_out;
    float* probs    = out;                                  // 1,048,576
    float* out_slot = out + 1048576;                        // 1,310,720
    float* out_len  = out + 1048576 + 1310720;              // 655,360
    float* out_wid  = out_len + 655360;                     // 655,360

    float* ws     = (float*)d_ws;
    float* gates  = ws;                      // 2,097,152 f32
    float* h      = ws + 2097152;            //   524,288
    float* logits = ws + 2621440;            // 1,048,576
    int*   pslot  = (int*)(ws + 3670016);    // 1024
    int*   pblock = (int*)(ws + 3671040);    // 1024
    float* pblen  = ws + 3672064;            // 1024
    float* pbwid  = ws + 3673088;            // 1024

    // gates = x@Wih^T + h0@Whh^T + bih + bhh   (1024 x 2048)
    gemm_bias<8><<<dim3(FOURH/64, Bsz/128), 256, 0, stream>>>(
        x, Wih, INDIM, h0, Whh, HID, bih, bhh, gates, FOURH);
    lstm_kernel<<<512, 256, 0, stream>>>(gates, c0, h);
    // logits = h@Wfc^T + bfc   (1024 x 1024)
    gemm_bias<4><<<dim3(NBNY/64, Bsz/64), 256, 0, stream>>>(
        h, Wfc, HID, nullptr, nullptr, 0, bfc, nullptr, logits, NBNY);
    softmax_fused<<<Bsz, 256, 0, stream>>>(logits, em, bmask, bcount, bsize, bwid, blen,
                                           probs, pslot, pblock, pblen, pbwid);
    finalize_kernel<<<5120, 256, 0, stream>>>(bslot, blen, bwid, pslot, pblock, pblen, pbwid,
                                              out_slot, out_len, out_wid);
}

// Round 5
// 730.926 us; speedup vs baseline: 1.1082x; 1.1082x over previous
//
#include <hip/hip_runtime.h>
#include <math.h>

#define Bsz 1024
#define PADL 127
#define HID 512
#define NBb 128
#define NYd 8
#define INDIM 640
#define MTRIP 10
#define MROW 8
#define NBNY 1024
#define FOURH 2048
#define KCAT 1152      // 640 + 512

typedef short  bf16x8 __attribute__((ext_vector_type(8)));
typedef float  f32x4  __attribute__((ext_vector_type(4)));
typedef unsigned short u16x8 __attribute__((ext_vector_type(8)));

__device__ __forceinline__ float sigf(float x){ return 1.0f/(1.0f+expf(-x)); }

__device__ __forceinline__ unsigned short bf16rn(float x){
    unsigned int u = __float_as_uint(x);
    unsigned int r = (u + 0x7FFFu + ((u>>16)&1u)) >> 16;
    return (unsigned short)r;
}

// ---- hi/lo bf16 split of concat([src1 K1 | src2 K2]) rows ----
// grid: rows*(K/8)/256 blocks; K = K1+K2 = 1152
__global__ __launch_bounds__(256) void convert_concat(
    const float* __restrict__ src1, const float* __restrict__ src2,
    unsigned short* __restrict__ dstH, unsigned short* __restrict__ dstL)
{
    int t = blockIdx.x*256 + threadIdx.x;
    int r  = t / 144;           // 1152/8 = 144 chunks per row
    int c8 = t - r*144;
    const float* p = (c8 < 80) ? (src1 + (size_t)r*INDIM + c8*8)
                               : (src2 + (size_t)r*HID + (c8-80)*8);
    float4 v0 = *(const float4*)p;
    float4 v1 = *(const float4*)(p+4);
    float v[8] = {v0.x,v0.y,v0.z,v0.w,v1.x,v1.y,v1.z,v1.w};
    u16x8 hv, lv;
    #pragma unroll
    for (int i=0;i<8;++i){
        unsigned short h = bf16rn(v[i]);
        float hf = __uint_as_float(((unsigned int)h)<<16);
        unsigned short l = bf16rn(v[i]-hf);
        hv[i] = h; lv[i] = l;
    }
    size_t base = (size_t)r*KCAT + c8*8;
    *(u16x8*)(dstH + base) = hv;
    *(u16x8*)(dstL + base) = lv;
}

// =====================================================================
// gates = Acat @ Bcat^T + bih + bhh via MFMA bf16x3 (hi/lo error split)
// Acat [1024][1152] (hi,lo bf16), Bcat [2048][1152] (hi,lo bf16)
// Tile 128(M) x 64(N), BK=32, 256 thr = 4 waves (2x2), wave-tile 64x32.
// =====================================================================
__global__ __launch_bounds__(256) void gemm_gates_mfma(
    const unsigned short* __restrict__ Ah_g, const unsigned short* __restrict__ Al_g,
    const unsigned short* __restrict__ Bh_g, const unsigned short* __restrict__ Bl_g,
    const float* __restrict__ bih, const float* __restrict__ bhh,
    float* __restrict__ gates)
{
    __shared__ __align__(16) unsigned short Ah_s[128*32];
    __shared__ __align__(16) unsigned short Al_s[128*32];
    __shared__ __align__(16) unsigned short Bh_s[64*32];
    __shared__ __align__(16) unsigned short Bl_s[64*32];

    const int t = threadIdx.x;
    const int lane = t & 63;
    const int w = t >> 6;
    const int wr = w >> 1, wc = w & 1;
    const int m0 = blockIdx.y*128, n0 = blockIdx.x*64;

    // staging maps (uint4 = 8 ushorts per load)
    const int fa0 = t*8;            // A issue 0: ushort flat idx
    const int fa1 = (256+t)*8;      // A issue 1
    const int fb  = t*8;            // B single issue
    const int ar0 = fa0>>5, ac0 = fa0&31;
    const int ar1 = fa1>>5, ac1 = fa1&31;
    const int brow = fb>>5, bcol = fb&31;

    f32x4 acc[4][2];
    #pragma unroll
    for (int m=0;m<4;++m){
        #pragma unroll
        for (int n=0;n<2;++n) acc[m][n] = (f32x4){0.f,0.f,0.f,0.f};
    }

    uint4 rah0, rah1, ral0, ral1, rbh, rbl;
    auto load6 = [&](int k0){
        rah0 = *(const uint4*)(Ah_g + (size_t)(m0+ar0)*KCAT + k0 + ac0);
        rah1 = *(const uint4*)(Ah_g + (size_t)(m0+ar1)*KCAT + k0 + ac1);
        ral0 = *(const uint4*)(Al_g + (size_t)(m0+ar0)*KCAT + k0 + ac0);
        ral1 = *(const uint4*)(Al_g + (size_t)(m0+ar1)*KCAT + k0 + ac1);
        rbh  = *(const uint4*)(Bh_g + (size_t)(n0+brow)*KCAT + k0 + bcol);
        rbl  = *(const uint4*)(Bl_g + (size_t)(n0+brow)*KCAT + k0 + bcol);
    };

    load6(0);
    for (int s=0; s<KCAT/32; ++s){
        __syncthreads();
        *(uint4*)&Ah_s[fa0] = rah0;  *(uint4*)&Ah_s[fa1] = rah1;
        *(uint4*)&Al_s[fa0] = ral0;  *(uint4*)&Al_s[fa1] = ral1;
        *(uint4*)&Bh_s[fb]  = rbh;   *(uint4*)&Bl_s[fb]  = rbl;
        __syncthreads();
        if (s+1 < KCAT/32) load6((s+1)*32);

        const int kc = (lane>>4)*8;
        bf16x8 afh[4], afl[4], bfh[2], bfl[2];
        #pragma unroll
        for (int m=0;m<4;++m){
            int idx = (wr*64 + m*16 + (lane&15))*32 + kc;
            afh[m] = *(const bf16x8*)&Ah_s[idx];
            afl[m] = *(const bf16x8*)&Al_s[idx];
        }
        #pragma unroll
        for (int n=0;n<2;++n){
            int idx = (wc*32 + n*16 + (lane&15))*32 + kc;
            bfh[n] = *(const bf16x8*)&Bh_s[idx];
            bfl[n] = *(const bf16x8*)&Bl_s[idx];
        }
        #pragma unroll
        for (int m=0;m<4;++m){
            #pragma unroll
            for (int n=0;n<2;++n){
                acc[m][n] = __builtin_amdgcn_mfma_f32_16x16x32_bf16(afh[m], bfh[n], acc[m][n], 0,0,0);
                acc[m][n] = __builtin_amdgcn_mfma_f32_16x16x32_bf16(afh[m], bfl[n], acc[m][n], 0,0,0);
                acc[m][n] = __builtin_amdgcn_mfma_f32_16x16x32_bf16(afl[m], bfh[n], acc[m][n], 0,0,0);
            }
        }
    }

    #pragma unroll
    for (int m=0;m<4;++m){
        #pragma unroll
        for (int n=0;n<2;++n){
            int row = m0 + wr*64 + m*16 + ((lane>>4)<<2);
            int col = n0 + wc*32 + n*16 + (lane&15);
            float bsum = bih[col] + bhh[col];
            #pragma unroll
            for (int q=0;q<4;++q)
                gates[(size_t)(row+q)*FOURH + col] = acc[m][n][q] + bsum;
        }
    }
}

// =====================================================================
// f32 GEMM (kept for argmax-critical fc): C = A@B^T + bias, 64x64 tile
// =====================================================================
__global__ __launch_bounds__(256) void gemm_fc_f32(
    const float* __restrict__ A, const float* __restrict__ B,
    const float* __restrict__ bias, float* __restrict__ C)
{
    __shared__ float As[2][16][68];
    __shared__ float Bs[2][16][68];
    const int tid = threadIdx.x;
    const int m0 = blockIdx.y*64, n0 = blockIdx.x*64;
    const int lr = tid>>2, lc = (tid&3)*4;
    const int tm = (tid>>4)*4, tn = (tid&15)*4;
    float acc[4][4] = {{0,0,0,0},{0,0,0,0},{0,0,0,0},{0,0,0,0}};

    float4 pa, pb;
    auto prefetch = [&](int k0){
        pa = *(const float4*)(A + (size_t)(m0+lr)*HID + k0 + lc);
        pb = *(const float4*)(B + (size_t)(n0+lr)*HID + k0 + lc);
    };
    auto stage = [&](int buf){
        As[buf][lc+0][lr]=pa.x; As[buf][lc+1][lr]=pa.y;
        As[buf][lc+2][lr]=pa.z; As[buf][lc+3][lr]=pa.w;
        Bs[buf][lc+0][lr]=pb.x; Bs[buf][lc+1][lr]=pb.y;
        Bs[buf][lc+2][lr]=pb.z; Bs[buf][lc+3][lr]=pb.w;
    };

    prefetch(0); stage(0); __syncthreads();
    int buf = 0;
    for (int s=0; s<HID/16; ++s){
        if (s+1 < HID/16) prefetch((s+1)*16);
        #pragma unroll
        for (int kk=0; kk<16; ++kk){
            float4 a = *(const float4*)&As[buf][kk][tm];
            float4 b = *(const float4*)&Bs[buf][kk][tn];
            float a4[4]={a.x,a.y,a.z,a.w}, b4[4]={b.x,b.y,b.z,b.w};
            #pragma unroll
            for (int i=0;i<4;i++)
                #pragma unroll
                for (int j=0;j<4;j++) acc[i][j] += a4[i]*b4[j];
        }
        if (s+1 < HID/16){ stage(buf^1); __syncthreads(); buf ^= 1; }
    }
    #pragma unroll
    for (int i=0;i<4;i++){
        int row = m0+tm+i;
        #pragma unroll
        for (int j=0;j<4;j++){
            int col = n0+tn+j;
            C[(size_t)row*NBNY + col] = acc[i][j] + bias[col];
        }
    }
}

// ---- LSTM elementwise (float4) ----
__global__ __launch_bounds__(256) void lstm_kernel(const float* __restrict__ gates,
    const float* __restrict__ c0, float* __restrict__ h)
{
    int idx = blockIdx.x*256 + threadIdx.x;       // < 1024*128
    int b = idx >> 7, j4 = (idx & 127)*4;
    const float* g = gates + (size_t)b*FOURH;
    float4 iv = *(const float4*)(g + j4);
    float4 fv = *(const float4*)(g + 512 + j4);
    float4 gv = *(const float4*)(g + 1024 + j4);
    float4 ov = *(const float4*)(g + 1536 + j4);
    float4 cv = *(const float4*)(c0 + (size_t)b*HID + j4);
    float4 hv;
    hv.x = sigf(ov.x)*tanhf(sigf(fv.x)*cv.x + sigf(iv.x)*tanhf(gv.x));
    hv.y = sigf(ov.y)*tanhf(sigf(fv.y)*cv.y + sigf(iv.y)*tanhf(gv.y));
    hv.z = sigf(ov.z)*tanhf(sigf(fv.z)*cv.z + sigf(iv.z)*tanhf(gv.z));
    hv.w = sigf(ov.w)*tanhf(sigf(fv.w)*cv.w + sigf(iv.w)*tanhf(gv.w));
    *(float4*)(h + (size_t)b*HID + j4) = hv;
}

// ---- any(encoder_mask row) with 4-int-chunk early exit ----
__device__ __forceinline__ int row_any(const int* __restrict__ p){
    #pragma unroll 1
    for (int j=0; j<124; j+=4){
        if (p[j] | p[j+1] | p[j+2] | p[j+3]) return 1;
    }
    return (p[124] | p[125] | p[126]) ? 1 : 0;
}

// ---- fused: yard feasibility + masked softmax + argmax + decode ----
__global__ __launch_bounds__(256) void softmax_fused(
    const float* __restrict__ logits, const int* __restrict__ em,
    const int* __restrict__ bmask, const int* __restrict__ bcount,
    const float* __restrict__ bsize, const float* __restrict__ bwid_in,
    const float* __restrict__ blen_in,
    float* __restrict__ probs,
    int* __restrict__ pslot, int* __restrict__ pblock,
    float* __restrict__ pblen, float* __restrict__ pbwid)
{
    int b = blockIdx.x, t = threadIdx.x;
    __shared__ float red[256];
    __shared__ int  redi[256];
    const float* lrow = logits + (size_t)b*NBNY;

    float ml[4]; float mymax = -INFINITY;
    #pragma unroll
    for (int r=0;r<4;++r){
        int c = t + r*256;
        int nb = c >> 3;
        int v = 0;
        if (bmask[b*NBb + nb] == 0)
            v = row_any(em + (size_t)(b*NBNY + c)*PADL);
        float m = v ? lrow[c] : -1e9f;
        ml[r] = m; mymax = fmaxf(mymax, m);
    }
    red[t]=mymax; __syncthreads();
    for (int s=128;s>0;s>>=1){ if(t<s) red[t]=fmaxf(red[t],red[t+s]); __syncthreads(); }
    float rowmax = red[0]; __syncthreads();

    float p[4]; float mysum=0.f;
    #pragma unroll
    for (int r=0;r<4;++r){ p[r]=expf(ml[r]-rowmax); mysum+=p[r]; }
    red[t]=mysum; __syncthreads();
    for (int s=128;s>0;s>>=1){ if(t<s) red[t]+=red[t+s]; __syncthreads(); }
    float inv = 1.0f/red[0]; __syncthreads();

    float bv=-INFINITY; int bi=0;
    #pragma unroll
    for (int r=0;r<4;++r){
        int c = t + r*256;
        float pr = p[r]*inv;
        probs[(size_t)b*NBNY + c] = pr;
        if (pr > bv){ bv=pr; bi=c; }     // in-thread cols ascend -> strict > = first max
    }
    red[t]=bv; redi[t]=bi; __syncthreads();
    for (int s=128;s>0;s>>=1){
        if (t<s){
            float ov=red[t+s]; int oi=redi[t+s];
            if (ov>red[t] || (ov==red[t] && oi<redi[t])){ red[t]=ov; redi[t]=oi; }
        }
        __syncthreads();
    }

    if (t==0){
        int a = redi[0];
        int blk = a / NYd, yard = a % NYd;
        int cur = bcount[b*NYd + yard];
        int base = ((b*NYd + yard)*MTRIP + cur)*MROW;
        float bestv = -INFINITY; int bests = 0;
        #pragma unroll
        for (int s=0;s<MROW;++s){
            float w = bwid_in[base+s];
            float l = blen_in[base+s];
            float cand = (w <= 10.0f) ? l : -1.0f;
            if (cand > bestv){ bestv=cand; bests=s; }   // first max
        }
        pslot[b]  = base + bests;
        pblock[b] = blk;
        pblen[b]  = bsize[(b*NBb + blk)*5 + 0];
        pbwid[b]  = bsize[(b*NBb + blk)*5 + 1];
    }
}

// ---- copy inputs -> outputs with single-element patches ----
__global__ __launch_bounds__(256) void finalize_kernel(const int* __restrict__ bslot,
    const float* __restrict__ blen_in, const float* __restrict__ bwid_in,
    const int* __restrict__ pslot, const int* __restrict__ pblock,
    const float* __restrict__ pblen, const float* __restrict__ pbwid,
    float* __restrict__ out_slot, float* __restrict__ out_len, float* __restrict__ out_wid)
{
    int i = blockIdx.x*256 + threadIdx.x;
    if (i < Bsz*NYd*MTRIP*MROW*2){               // 1,310,720
        int b = i / (NYd*MTRIP*MROW*2);          // /1280
        float v = (float)bslot[i];
        if (i == pslot[b]*2 + 1) v = (float)pblock[b];
        out_slot[i] = v;
    }
    if (i < Bsz*NYd*MTRIP*MROW){                 // 655,360
        int b = i / (NYd*MTRIP*MROW);            // /640
        float l = blen_in[i], w = bwid_in[i];
        if (i == pslot[b]){ l = fmaxf(l, pblen[b]); w = w + pbwid[b]; }
        out_len[i] = l;
        out_wid[i] = w;
    }
}

extern "C" void kernel_launch(void* const* d_in, const int* in_sizes, int n_in,
                              void* d_out, int out_size, void* d_ws, size_t ws_size,
                              hipStream_t stream)
{
    const float* x    = (const float*)d_in[0];
    const float* h0   = (const float*)d_in[1];
    const float* c0   = (const float*)d_in[2];
    const float* Wih  = (const float*)d_in[3];
    const float* Whh  = (const float*)d_in[4];
    const float* bih  = (const float*)d_in[5];
    const float* bhh  = (const float*)d_in[6];
    const float* Wfc  = (const float*)d_in[7];
    const float* bfc  = (const float*)d_in[8];
    const float* bsize= (const float*)d_in[9];
    const float* blen = (const float*)d_in[10];
    const float* bwid = (const float*)d_in[11];
    const int*   em   = (const int*)d_in[12];
    const int*   bmask= (const int*)d_in[13];
    const int*   bcount=(const int*)d_in[14];
    const int*   bslot= (const int*)d_in[15];

    float* out      = (float*)d_out;
    float* probs    = out;                                  // 1,048,576
    float* out_slot = out + 1048576;                        // 1,310,720
    float* out_len  = out + 1048576 + 1310720;              // 655,360
    float* out_wid  = out_len + 655360;                     // 655,360

    float* ws     = (float*)d_ws;
    float* gates  = ws;                                 // 2,097,152 f32
    float* h      = ws + 2097152;                       //   524,288
    float* logits = ws + 2621440;                       // 1,048,576
    unsigned short* Ah = (unsigned short*)(ws + 3670016);   // 1024*1152 bf16 = 589,824 f32-slots
    unsigned short* Al = (unsigned short*)(ws + 4259840);
    unsigned short* Bh = (unsigned short*)(ws + 4849664);   // 2048*1152 bf16 = 1,179,648 slots
    unsigned short* Bl = (unsigned short*)(ws + 6029312);
    int*   pslot  = (int*)(ws + 7208960);
    int*   pblock = (int*)(ws + 7209984);
    float* pblen  = ws + 7211008;
    float* pbwid  = ws + 7212032;

    convert_concat<<<576, 256, 0, stream>>>(x, h0, Ah, Al);       // A = [x | h0]
    convert_concat<<<1152, 256, 0, stream>>>(Wih, Whh, Bh, Bl);   // B = [Wih | Whh]
    gemm_gates_mfma<<<dim3(FOURH/64, Bsz/128), 256, 0, stream>>>(
        Ah, Al, Bh, Bl, bih, bhh, gates);
    lstm_kernel<<<512, 256, 0, stream>>>(gates, c0, h);
    gemm_fc_f32<<<dim3(NBNY/64, Bsz/64), 256, 0, stream>>>(h, Wfc, bfc, logits);
    softmax_fused<<<Bsz, 256, 0, stream>>>(logits, em, bmask, bcount, bsize, bwid, blen,
                                           probs, pslot, pblock, pblen, pbwid);
    finalize_kernel<<<5120, 256, 0, stream>>>(bslot, blen, bwid, pslot, pblock, pblen, pbwid,
                                              out_slot, out_len, out_wid);
}

// Round 6
// 720.176 us; speedup vs baseline: 1.1247x; 1.0149x over previous
//
#include <hip/hip_runtime.h>
#include <math.h>

#define Bsz 1024
#define PADL 127
#define HID 512
#define NBb 128
#define NYd 8
#define INDIM 640
#define MTRIP 10
#define MROW 8
#define NBNY 1024
#define FOURH 2048
#define KCAT 1152      // 640 + 512

typedef short  bf16x8 __attribute__((ext_vector_type(8)));
typedef float  f32x4  __attribute__((ext_vector_type(4)));
typedef unsigned short u16x8 __attribute__((ext_vector_type(8)));
typedef unsigned short u16x4 __attribute__((ext_vector_type(4)));

__device__ __forceinline__ float sigf(float x){ return 1.0f/(1.0f+expf(-x)); }

__device__ __forceinline__ unsigned short bf16rn(float x){
    unsigned int u = __float_as_uint(x);
    unsigned int r = (u + 0x7FFFu + ((u>>16)&1u)) >> 16;
    return (unsigned short)r;
}
__device__ __forceinline__ float bf2f(unsigned short h){
    return __uint_as_float(((unsigned int)h)<<16);
}

// =====================================================================
// convert_all: one launch, three jobs by block range.
//  job A [0,576):    [x | h0] rows -> Ah, Al        (1024 x 1152)
//  job B [576,1728): [Wih | Whh] rows -> Bh, Bl     (2048 x 1152)
//  job W [1728,1984): Wfc -> W1, W2, W3 (3-way split) (1024 x 512)
// =====================================================================
__global__ __launch_bounds__(256) void convert_all(
    const float* __restrict__ x,   const float* __restrict__ h0,
    const float* __restrict__ Wih, const float* __restrict__ Whh,
    const float* __restrict__ Wfc,
    unsigned short* __restrict__ Ah, unsigned short* __restrict__ Al,
    unsigned short* __restrict__ Bh, unsigned short* __restrict__ Bl,
    unsigned short* __restrict__ W1, unsigned short* __restrict__ W2,
    unsigned short* __restrict__ W3)
{
    int blk = blockIdx.x;
    if (blk < 1728){
        const float* s1; const float* s2;
        unsigned short* dH; unsigned short* dL;
        int t;
        if (blk < 576){ s1=x; s2=h0; dH=Ah; dL=Al; t = blk*256 + threadIdx.x; }
        else          { s1=Wih; s2=Whh; dH=Bh; dL=Bl; t = (blk-576)*256 + threadIdx.x; }
        int r  = t / 144;           // 1152/8 chunks per row
        int c8 = t - r*144;
        const float* p = (c8 < 80) ? (s1 + (size_t)r*INDIM + c8*8)
                                   : (s2 + (size_t)r*HID + (c8-80)*8);
        float4 v0 = *(const float4*)p;
        float4 v1 = *(const float4*)(p+4);
        float v[8] = {v0.x,v0.y,v0.z,v0.w,v1.x,v1.y,v1.z,v1.w};
        u16x8 hv, lv;
        #pragma unroll
        for (int i=0;i<8;++i){
            unsigned short h = bf16rn(v[i]);
            unsigned short l = bf16rn(v[i]-bf2f(h));
            hv[i] = h; lv[i] = l;
        }
        size_t base = (size_t)r*KCAT + c8*8;
        *(u16x8*)(dH + base) = hv;
        *(u16x8*)(dL + base) = lv;
    } else {
        int t = (blk-1728)*256 + threadIdx.x;      // < 65536
        int r  = t >> 6;           // row < 1024
        int c8 = t & 63;           // 512/8 chunks
        const float* p = Wfc + (size_t)r*HID + c8*8;
        float4 v0 = *(const float4*)p;
        float4 v1 = *(const float4*)(p+4);
        float v[8] = {v0.x,v0.y,v0.z,v0.w,v1.x,v1.y,v1.z,v1.w};
        u16x8 w1, w2, w3;
        #pragma unroll
        for (int i=0;i<8;++i){
            unsigned short a1 = bf16rn(v[i]);
            float r1 = v[i] - bf2f(a1);
            unsigned short a2 = bf16rn(r1);
            unsigned short a3 = bf16rn(r1 - bf2f(a2));
            w1[i]=a1; w2[i]=a2; w3[i]=a3;
        }
        size_t base = (size_t)r*HID + c8*8;
        *(u16x8*)(W1 + base) = w1;
        *(u16x8*)(W2 + base) = w2;
        *(u16x8*)(W3 + base) = w3;
    }
}

// =====================================================================
// gates = Acat @ Bcat^T + bih + bhh via MFMA bf16x3 (hi/lo error split)
// Tile 128(M) x 64(N), BK=32, 256 thr = 4 waves (2x2), wave-tile 64x32.
// (unchanged from passing R5 kernel)
// =====================================================================
__global__ __launch_bounds__(256) void gemm_gates_mfma(
    const unsigned short* __restrict__ Ah_g, const unsigned short* __restrict__ Al_g,
    const unsigned short* __restrict__ Bh_g, const unsigned short* __restrict__ Bl_g,
    const float* __restrict__ bih, const float* __restrict__ bhh,
    float* __restrict__ gates)
{
    __shared__ __align__(16) unsigned short Ah_s[128*32];
    __shared__ __align__(16) unsigned short Al_s[128*32];
    __shared__ __align__(16) unsigned short Bh_s[64*32];
    __shared__ __align__(16) unsigned short Bl_s[64*32];

    const int t = threadIdx.x;
    const int lane = t & 63;
    const int w = t >> 6;
    const int wr = w >> 1, wc = w & 1;
    const int m0 = blockIdx.y*128, n0 = blockIdx.x*64;

    const int fa0 = t*8;
    const int fa1 = (256+t)*8;
    const int fb  = t*8;
    const int ar0 = fa0>>5, ac0 = fa0&31;
    const int ar1 = fa1>>5, ac1 = fa1&31;
    const int brow = fb>>5, bcol = fb&31;

    f32x4 acc[4][2];
    #pragma unroll
    for (int m=0;m<4;++m){
        #pragma unroll
        for (int n=0;n<2;++n) acc[m][n] = (f32x4){0.f,0.f,0.f,0.f};
    }

    uint4 rah0, rah1, ral0, ral1, rbh, rbl;
    auto load6 = [&](int k0){
        rah0 = *(const uint4*)(Ah_g + (size_t)(m0+ar0)*KCAT + k0 + ac0);
        rah1 = *(const uint4*)(Ah_g + (size_t)(m0+ar1)*KCAT + k0 + ac1);
        ral0 = *(const uint4*)(Al_g + (size_t)(m0+ar0)*KCAT + k0 + ac0);
        ral1 = *(const uint4*)(Al_g + (size_t)(m0+ar1)*KCAT + k0 + ac1);
        rbh  = *(const uint4*)(Bh_g + (size_t)(n0+brow)*KCAT + k0 + bcol);
        rbl  = *(const uint4*)(Bl_g + (size_t)(n0+brow)*KCAT + k0 + bcol);
    };

    load6(0);
    for (int s=0; s<KCAT/32; ++s){
        __syncthreads();
        *(uint4*)&Ah_s[fa0] = rah0;  *(uint4*)&Ah_s[fa1] = rah1;
        *(uint4*)&Al_s[fa0] = ral0;  *(uint4*)&Al_s[fa1] = ral1;
        *(uint4*)&Bh_s[fb]  = rbh;   *(uint4*)&Bl_s[fb]  = rbl;
        __syncthreads();
        if (s+1 < KCAT/32) load6((s+1)*32);

        const int kc = (lane>>4)*8;
        bf16x8 afh[4], afl[4], bfh[2], bfl[2];
        #pragma unroll
        for (int m=0;m<4;++m){
            int idx = (wr*64 + m*16 + (lane&15))*32 + kc;
            afh[m] = *(const bf16x8*)&Ah_s[idx];
            afl[m] = *(const bf16x8*)&Al_s[idx];
        }
        #pragma unroll
        for (int n=0;n<2;++n){
            int idx = (wc*32 + n*16 + (lane&15))*32 + kc;
            bfh[n] = *(const bf16x8*)&Bh_s[idx];
            bfl[n] = *(const bf16x8*)&Bl_s[idx];
        }
        #pragma unroll
        for (int m=0;m<4;++m){
            #pragma unroll
            for (int n=0;n<2;++n){
                acc[m][n] = __builtin_amdgcn_mfma_f32_16x16x32_bf16(afh[m], bfh[n], acc[m][n], 0,0,0);
                acc[m][n] = __builtin_amdgcn_mfma_f32_16x16x32_bf16(afh[m], bfl[n], acc[m][n], 0,0,0);
                acc[m][n] = __builtin_amdgcn_mfma_f32_16x16x32_bf16(afl[m], bfh[n], acc[m][n], 0,0,0);
            }
        }
    }

    #pragma unroll
    for (int m=0;m<4;++m){
        #pragma unroll
        for (int n=0;n<2;++n){
            int row = m0 + wr*64 + m*16 + ((lane>>4)<<2);
            int col = n0 + wc*32 + n*16 + (lane&15);
            float bsum = bih[col] + bhh[col];
            #pragma unroll
            for (int q=0;q<4;++q)
                gates[(size_t)(row+q)*FOURH + col] = acc[m][n][q] + bsum;
        }
    }
}

// ---- LSTM elementwise + 3-way bf16 split of h ----
__global__ __launch_bounds__(256) void lstm_kernel(const float* __restrict__ gates,
    const float* __restrict__ c0,
    unsigned short* __restrict__ h1, unsigned short* __restrict__ h2,
    unsigned short* __restrict__ h3)
{
    int idx = blockIdx.x*256 + threadIdx.x;       // < 1024*128
    int b = idx >> 7, j4 = (idx & 127)*4;
    const float* g = gates + (size_t)b*FOURH;
    float4 iv = *(const float4*)(g + j4);
    float4 fv = *(const float4*)(g + 512 + j4);
    float4 gv = *(const float4*)(g + 1024 + j4);
    float4 ov = *(const float4*)(g + 1536 + j4);
    float4 cv = *(const float4*)(c0 + (size_t)b*HID + j4);
    float hv[4];
    hv[0] = sigf(ov.x)*tanhf(sigf(fv.x)*cv.x + sigf(iv.x)*tanhf(gv.x));
    hv[1] = sigf(ov.y)*tanhf(sigf(fv.y)*cv.y + sigf(iv.y)*tanhf(gv.y));
    hv[2] = sigf(ov.z)*tanhf(sigf(fv.z)*cv.z + sigf(iv.z)*tanhf(gv.z));
    hv[3] = sigf(ov.w)*tanhf(sigf(fv.w)*cv.w + sigf(iv.w)*tanhf(gv.w));
    u16x4 o1, o2, o3;
    #pragma unroll
    for (int i=0;i<4;++i){
        unsigned short a1 = bf16rn(hv[i]);
        float r1 = hv[i] - bf2f(a1);
        unsigned short a2 = bf16rn(r1);
        unsigned short a3 = bf16rn(r1 - bf2f(a2));
        o1[i]=a1; o2[i]=a2; o3[i]=a3;
    }
    size_t base = (size_t)b*HID + j4;
    *(u16x4*)(h1 + base) = o1;
    *(u16x4*)(h2 + base) = o2;
    *(u16x4*)(h3 + base) = o3;
}

// =====================================================================
// logits = h @ Wfc^T + bfc via MFMA, 3-way split, 6 products
// (a1b1 + a1b2 + a2b1 + a1b3 + a2b2 + a3b1: dropped terms ~2^-27 rel,
//  below f32 accumulation noise -> argmax-safe)
// Tile 64x64, BK=32, 256 thr = 4 waves (2x2), wave-tile 32x32.
// =====================================================================
__global__ __launch_bounds__(256) void gemm_fc_mfma(
    const unsigned short* __restrict__ A1, const unsigned short* __restrict__ A2,
    const unsigned short* __restrict__ A3,
    const unsigned short* __restrict__ B1, const unsigned short* __restrict__ B2,
    const unsigned short* __restrict__ B3,
    const float* __restrict__ bfc, float* __restrict__ logits)
{
    __shared__ __align__(16) unsigned short As[3][64*32];
    __shared__ __align__(16) unsigned short Bs[3][64*32];

    const int t = threadIdx.x;
    const int lane = t & 63;
    const int w = t >> 6;
    const int wr = w >> 1, wc = w & 1;
    const int m0 = blockIdx.y*64, n0 = blockIdx.x*64;

    const int fr = (t*8)>>5, fcol = (t*8)&31;   // one uint4 per plane per thread

    f32x4 acc[2][2];
    #pragma unroll
    for (int m=0;m<2;++m){
        #pragma unroll
        for (int n=0;n<2;++n) acc[m][n] = (f32x4){0.f,0.f,0.f,0.f};
    }

    uint4 ra1, ra2, ra3, rb1, rb2, rb3;
    auto load6 = [&](int k0){
        size_t aoff = (size_t)(m0+fr)*HID + k0 + fcol;
        size_t boff = (size_t)(n0+fr)*HID + k0 + fcol;
        ra1 = *(const uint4*)(A1 + aoff);
        ra2 = *(const uint4*)(A2 + aoff);
        ra3 = *(const uint4*)(A3 + aoff);
        rb1 = *(const uint4*)(B1 + boff);
        rb2 = *(const uint4*)(B2 + boff);
        rb3 = *(const uint4*)(B3 + boff);
    };

    load6(0);
    const int fa = t*8;
    for (int s=0; s<HID/32; ++s){
        __syncthreads();
        *(uint4*)&As[0][fa] = ra1;  *(uint4*)&As[1][fa] = ra2;  *(uint4*)&As[2][fa] = ra3;
        *(uint4*)&Bs[0][fa] = rb1;  *(uint4*)&Bs[1][fa] = rb2;  *(uint4*)&Bs[2][fa] = rb3;
        __syncthreads();
        if (s+1 < HID/32) load6((s+1)*32);

        const int kc = (lane>>4)*8;
        bf16x8 af[3][2], bf[3][2];
        #pragma unroll
        for (int m=0;m<2;++m){
            int idx = (wr*32 + m*16 + (lane&15))*32 + kc;
            #pragma unroll
            for (int p=0;p<3;++p) af[p][m] = *(const bf16x8*)&As[p][idx];
        }
        #pragma unroll
        for (int n=0;n<2;++n){
            int idx = (wc*32 + n*16 + (lane&15))*32 + kc;
            #pragma unroll
            for (int p=0;p<3;++p) bf[p][n] = *(const bf16x8*)&Bs[p][idx];
        }
        #pragma unroll
        for (int m=0;m<2;++m){
            #pragma unroll
            for (int n=0;n<2;++n){
                acc[m][n] = __builtin_amdgcn_mfma_f32_16x16x32_bf16(af[0][m], bf[0][n], acc[m][n], 0,0,0);
                acc[m][n] = __builtin_amdgcn_mfma_f32_16x16x32_bf16(af[0][m], bf[1][n], acc[m][n], 0,0,0);
                acc[m][n] = __builtin_amdgcn_mfma_f32_16x16x32_bf16(af[1][m], bf[0][n], acc[m][n], 0,0,0);
                acc[m][n] = __builtin_amdgcn_mfma_f32_16x16x32_bf16(af[0][m], bf[2][n], acc[m][n], 0,0,0);
                acc[m][n] = __builtin_amdgcn_mfma_f32_16x16x32_bf16(af[1][m], bf[1][n], acc[m][n], 0,0,0);
                acc[m][n] = __builtin_amdgcn_mfma_f32_16x16x32_bf16(af[2][m], bf[0][n], acc[m][n], 0,0,0);
            }
        }
    }

    #pragma unroll
    for (int m=0;m<2;++m){
        #pragma unroll
        for (int n=0;n<2;++n){
            int row = m0 + wr*32 + m*16 + ((lane>>4)<<2);
            int col = n0 + wc*32 + n*16 + (lane&15);
            float bsum = bfc[col];
            #pragma unroll
            for (int q=0;q<4;++q)
                logits[(size_t)(row+q)*NBNY + col] = acc[m][n][q] + bsum;
        }
    }
}

// ---- any(encoder_mask row) with 4-int-chunk early exit ----
__device__ __forceinline__ int row_any(const int* __restrict__ p){
    #pragma unroll 1
    for (int j=0; j<124; j+=4){
        if (p[j] | p[j+1] | p[j+2] | p[j+3]) return 1;
    }
    return (p[124] | p[125] | p[126]) ? 1 : 0;
}

// ---- fused: yard feasibility + masked softmax + argmax + decode ----
__global__ __launch_bounds__(256) void softmax_fused(
    const float* __restrict__ logits, const int* __restrict__ em,
    const int* __restrict__ bmask, const int* __restrict__ bcount,
    const float* __restrict__ bsize, const float* __restrict__ bwid_in,
    const float* __restrict__ blen_in,
    float* __restrict__ probs,
    int* __restrict__ pslot, int* __restrict__ pblock,
    float* __restrict__ pblen, float* __restrict__ pbwid)
{
    int b = blockIdx.x, t = threadIdx.x;
    __shared__ float red[256];
    __shared__ int  redi[256];
    const float* lrow = logits + (size_t)b*NBNY;

    float ml[4]; float mymax = -INFINITY;
    #pragma unroll
    for (int r=0;r<4;++r){
        int c = t + r*256;
        int nb = c >> 3;
        int v = 0;
        if (bmask[b*NBb + nb] == 0)
            v = row_any(em + (size_t)(b*NBNY + c)*PADL);
        float m = v ? lrow[c] : -1e9f;
        ml[r] = m; mymax = fmaxf(mymax, m);
    }
    red[t]=mymax; __syncthreads();
    for (int s=128;s>0;s>>=1){ if(t<s) red[t]=fmaxf(red[t],red[t+s]); __syncthreads(); }
    float rowmax = red[0]; __syncthreads();

    float p[4]; float mysum=0.f;
    #pragma unroll
    for (int r=0;r<4;++r){ p[r]=expf(ml[r]-rowmax); mysum+=p[r]; }
    red[t]=mysum; __syncthreads();
    for (int s=128;s>0;s>>=1){ if(t<s) red[t]+=red[t+s]; __syncthreads(); }
    float inv = 1.0f/red[0]; __syncthreads();

    float bv=-INFINITY; int bi=0;
    #pragma unroll
    for (int r=0;r<4;++r){
        int c = t + r*256;
        float pr = p[r]*inv;
        probs[(size_t)b*NBNY + c] = pr;
        if (pr > bv){ bv=pr; bi=c; }     // in-thread cols ascend -> strict > = first max
    }
    red[t]=bv; redi[t]=bi; __syncthreads();
    for (int s=128;s>0;s>>=1){
        if (t<s){
            float ov=red[t+s]; int oi=redi[t+s];
            if (ov>red[t] || (ov==red[t] && oi<redi[t])){ red[t]=ov; redi[t]=oi; }
        }
        __syncthreads();
    }

    if (t==0){
        int a = redi[0];
        int blk = a / NYd, yard = a % NYd;
        int cur = bcount[b*NYd + yard];
        int base = ((b*NYd + yard)*MTRIP + cur)*MROW;
        float bestv = -INFINITY; int bests = 0;
        #pragma unroll
        for (int s=0;s<MROW;++s){
            float w = bwid_in[base+s];
            float l = blen_in[base+s];
            float cand = (w <= 10.0f) ? l : -1.0f;
            if (cand > bestv){ bestv=cand; bests=s; }   // first max
        }
        pslot[b]  = base + bests;
        pblock[b] = blk;
        pblen[b]  = bsize[(b*NBb + blk)*5 + 0];
        pbwid[b]  = bsize[(b*NBb + blk)*5 + 1];
    }
}

// ---- copy inputs -> outputs with single-element patches ----
__global__ __launch_bounds__(256) void finalize_kernel(const int* __restrict__ bslot,
    const float* __restrict__ blen_in, const float* __restrict__ bwid_in,
    const int* __restrict__ pslot, const int* __restrict__ pblock,
    const float* __restrict__ pblen, const float* __restrict__ pbwid,
    float* __restrict__ out_slot, float* __restrict__ out_len, float* __restrict__ out_wid)
{
    int i = blockIdx.x*256 + threadIdx.x;
    if (i < Bsz*NYd*MTRIP*MROW*2){               // 1,310,720
        int b = i / (NYd*MTRIP*MROW*2);          // /1280
        float v = (float)bslot[i];
        if (i == pslot[b]*2 + 1) v = (float)pblock[b];
        out_slot[i] = v;
    }
    if (i < Bsz*NYd*MTRIP*MROW){                 // 655,360
        int b = i / (NYd*MTRIP*MROW);            // /640
        float l = blen_in[i], w = bwid_in[i];
        if (i == pslot[b]){ l = fmaxf(l, pblen[b]); w = w + pbwid[b]; }
        out_len[i] = l;
        out_wid[i] = w;
    }
}

extern "C" void kernel_launch(void* const* d_in, const int* in_sizes, int n_in,
                              void* d_out, int out_size, void* d_ws, size_t ws_size,
                              hipStream_t stream)
{
    const float* x    = (const float*)d_in[0];
    const float* h0   = (const float*)d_in[1];
    const float* c0   = (const float*)d_in[2];
    const float* Wih  = (const float*)d_in[3];
    const float* Whh  = (const float*)d_in[4];
    const float* bih  = (const float*)d_in[5];
    const float* bhh  = (const float*)d_in[6];
    const float* Wfc  = (const float*)d_in[7];
    const float* bfc  = (const float*)d_in[8];
    const float* bsize= (const float*)d_in[9];
    const float* blen = (const float*)d_in[10];
    const float* bwid = (const float*)d_in[11];
    const int*   em   = (const int*)d_in[12];
    const int*   bmask= (const int*)d_in[13];
    const int*   bcount=(const int*)d_in[14];
    const int*   bslot= (const int*)d_in[15];

    float* out      = (float*)d_out;
    float* probs    = out;                                  // 1,048,576
    float* out_slot = out + 1048576;                        // 1,310,720
    float* out_len  = out + 1048576 + 1310720;              // 655,360
    float* out_wid  = out_len + 655360;                     // 655,360

    float* ws = (float*)d_ws;                  // offsets in f32 slots
    float* gates  = ws;                        // 2,097,152
    float* logits = ws + 2097152;              // 1,048,576
    unsigned short* Ah = (unsigned short*)(ws + 3145728);   // 1024*1152 u16
    unsigned short* Al = (unsigned short*)(ws + 3735552);
    unsigned short* Bh = (unsigned short*)(ws + 4325376);   // 2048*1152 u16
    unsigned short* Bl = (unsigned short*)(ws + 5505024);
    unsigned short* h1 = (unsigned short*)(ws + 6684672);   // 1024*512 u16
    unsigned short* h2 = (unsigned short*)(ws + 6946816);
    unsigned short* h3 = (unsigned short*)(ws + 7208960);
    unsigned short* W1 = (unsigned short*)(ws + 7471104);   // 1024*512 u16
    unsigned short* W2 = (unsigned short*)(ws + 7733248);
    unsigned short* W3 = (unsigned short*)(ws + 7995392);
    int*   pslot  = (int*)(ws + 8257536);
    int*   pblock = (int*)(ws + 8258560);
    float* pblen  = ws + 8259584;
    float* pbwid  = ws + 8260608;

    convert_all<<<1984, 256, 0, stream>>>(x, h0, Wih, Whh, Wfc,
                                          Ah, Al, Bh, Bl, W1, W2, W3);
    gemm_gates_mfma<<<dim3(FOURH/64, Bsz/128), 256, 0, stream>>>(
        Ah, Al, Bh, Bl, bih, bhh, gates);
    lstm_kernel<<<512, 256, 0, stream>>>(gates, c0, h1, h2, h3);
    gemm_fc_mfma<<<dim3(NBNY/64, Bsz/64), 256, 0, stream>>>(
        h1, h2, h3, W1, W2, W3, bfc, logits);
    softmax_fused<<<Bsz, 256, 0, stream>>>(logits, em, bmask, bcount, bsize, bwid, blen,
                                           probs, pslot, pblock, pblen, pbwid);
    finalize_kernel<<<5120, 256, 0, stream>>>(bslot, blen, bwid, pslot, pblock, pblen, pbwid,
                                              out_slot, out_len, out_wid);
}